// Round 1
// 1035.434 us; speedup vs baseline: 1.3989x; 1.3989x over previous
//
#include <hip/hip_runtime.h>
#include <cmath>

#define Bq 64
#define Lq 2048
#define Hq 8
#define Eq 64
#define Mq 64
#define Oq 64

static __device__ __forceinline__ void rot_step(float& c, float& s, float cm, float sm) {
  float cn = fmaf(c, cm, -s * sm);
  float sn = fmaf(s, cm, c * sm);
  c = cn; s = sn;
}

// ---------------------------------------------------------------------------
// K1: truncated 64-mode DFT along L for q and k, with Hermitian fold:
//   X[m] = q[0] + (-1)^m q[1024]
//        + sum_{l=1}^{1023} (q[l]+q[2048-l]) cos(th) - i (q[l]-q[2048-l]) sin(th)
// Half the FMAs of the direct form. grid (H, B, 2), block 256.
// Thread tile 8e x 2m; rotation twiddles refreshed per 16-step round from an
// exact 128-entry table (refresh angle = 2*pi*(m*r)/128 -> index (m*r)&127),
// which also kills the old 16-way strided bank conflicts on refresh.
// Qft/Kft layout: [b][h][e][m] float2 (r, i) with rfft sign (i = -sum q*sin).
// ---------------------------------------------------------------------------
__global__ __launch_bounds__(256) void dft64_kernel(
    const float* __restrict__ q, const float* __restrict__ k,
    float2* __restrict__ Qft, float2* __restrict__ Kft) {
  const int h = blockIdx.x, b = blockIdx.y;
  const float* __restrict__ src = blockIdx.z ? k : q;
  float2* __restrict__ dst = blockIdx.z ? Kft : Qft;
  const int tid = threadIdx.x;

  __shared__ float2 tw128[128];                 // (cos,sin)(2*pi*j/128), exact
  __shared__ float2 twm[64];                    // (cos,sin)(2*pi*m/2048), exact
  __shared__ __align__(16) float us[2][16 * 64];  // u[l][e] = q[l]+q[2048-l]
  __shared__ __align__(16) float vs[2][16 * 64];  // v[l][e] = q[l]-q[2048-l]

  if (tid < 128) {
    double ang = (double)tid * 4.9087385212340517e-2;  // 2*pi/128
    double sn, cs;
    sincos(ang, &sn, &cs);
    tw128[tid] = make_float2((float)cs, (float)sn);
  } else if (tid < 192) {
    double ang = (double)(tid - 128) * 3.0679615757712823e-3;  // 2*pi/2048
    double sn, cs;
    sincos(ang, &sn, &cs);
    twm[tid - 128] = make_float2((float)cs, (float)sn);
  }

  const int e0 = (tid >> 5) << 3;   // 8 e per thread
  const int m0 = (tid & 31) << 1;   // 2 m per thread

  // staging: 16 l-rows per round, 16 lanes x float4 cover 64 e per row
  const int lrow = tid >> 4;
  const int lcol = (tid & 15) << 2;
  const float* __restrict__ base = src + (size_t)b * (Lq * Hq * Eq) + (size_t)h * Eq;

  float4 a = *(const float4*)(base + (size_t)lrow * (Hq * Eq) + lcol);
  float4 bb;
  if (lrow == 0) {
    bb = make_float4(0.f, 0.f, 0.f, 0.f);       // l=0 has no mirror partner
  } else {
    bb = *(const float4*)(base + (size_t)(2048 - lrow) * (Hq * Eq) + lcol);
  }

  __syncthreads();                               // tables ready

  float cm[2], sm[2];
#pragma unroll
  for (int j = 0; j < 2; ++j) { float2 w = twm[m0 + j]; cm[j] = w.x; sm[j] = w.y; }

  float qr[8][2] = {}, qi[8][2] = {};

  for (int r = 0; r < 64; ++r) {
    float* __restrict__ ub = us[r & 1];
    float* __restrict__ vb = vs[r & 1];
    *(float4*)&ub[lrow * 64 + lcol] =
        make_float4(a.x + bb.x, a.y + bb.y, a.z + bb.z, a.w + bb.w);
    *(float4*)&vb[lrow * 64 + lcol] =
        make_float4(a.x - bb.x, a.y - bb.y, a.z - bb.z, a.w - bb.w);
    __syncthreads();
    if (r + 1 < 64) {
      const int l = (r + 1) * 16 + lrow;                      // 16..1023
      a  = *(const float4*)(base + (size_t)l * (Hq * Eq) + lcol);
      bb = *(const float4*)(base + (size_t)(2048 - l) * (Hq * Eq) + lcol);
    }
    float c[2], s[2];
#pragma unroll
    for (int j = 0; j < 2; ++j) {   // exact refresh: angle = 2*pi*(m*r)/128
      float2 w = tw128[((m0 + j) * r) & 127];
      c[j] = w.x; s[j] = w.y;
    }
#pragma unroll
    for (int tt = 0; tt < 16; ++tt) {
      const float4 u0 = *(const float4*)&ub[tt * 64 + e0];
      const float4 u1 = *(const float4*)&ub[tt * 64 + e0 + 4];
      const float4 v0 = *(const float4*)&vb[tt * 64 + e0];
      const float4 v1 = *(const float4*)&vb[tt * 64 + e0 + 4];
      const float ue[8] = {u0.x, u0.y, u0.z, u0.w, u1.x, u1.y, u1.z, u1.w};
      const float ve[8] = {v0.x, v0.y, v0.z, v0.w, v1.x, v1.y, v1.z, v1.w};
#pragma unroll
      for (int j = 0; j < 2; ++j) {
        const float cc = c[j], ss = s[j];
#pragma unroll
        for (int i = 0; i < 8; ++i) {
          qr[i][j] = fmaf(ue[i], cc, qr[i][j]);
          qi[i][j] = fmaf(ve[i], ss, qi[i][j]);
        }
        rot_step(c[j], s[j], cm[j], sm[j]);
      }
    }
  }

  // l = 1024 term: contributes (-1)^m * q[1024][e] to Re only.
  // m0 is even, so j=0 -> +, j=1 -> -.
  {
    const float* __restrict__ p = base + (size_t)1024 * (Hq * Eq);
    const float4 qa = *(const float4*)(p + e0);
    const float4 qb = *(const float4*)(p + e0 + 4);
    const float q1024[8] = {qa.x, qa.y, qa.z, qa.w, qb.x, qb.y, qb.z, qb.w};
#pragma unroll
    for (int i = 0; i < 8; ++i) {
      qr[i][0] += q1024[i];
      qr[i][1] -= q1024[i];
    }
  }

  float2* __restrict__ o = dst + (size_t)(b * Hq + h) * (Eq * Mq);
#pragma unroll
  for (int i = 0; i < 8; ++i) {
    *(float4*)&o[(e0 + i) * Mq + m0] =
        make_float4(qr[i][0], -qi[i][0], qr[i][1], -qi[i][1]);
  }
}

// ---------------------------------------------------------------------------
// K2: per (b,h): A = Q^T K (complex, no conj), T = ctanh(A),
// xqkv = sum_y T[x,y] K[e,y], G[o,x] = scale_x * sum_e xqkv[e,x] * W[h,e,o,x].
// grid (H, B), block 256. LDS: Qs (-> T), Ks (-> xqkv), 64 KB total.
// ---------------------------------------------------------------------------
__global__ __launch_bounds__(256) void attn_kernel(
    const float2* __restrict__ Qft, const float2* __restrict__ Kft,
    const float* __restrict__ w1r, const float* __restrict__ w1i,
    float2* __restrict__ G) {
  const int h = blockIdx.x, b = blockIdx.y;
  const int tid = threadIdx.x;

  __shared__ __align__(16) float2 Qs[4096];   // Q[e][x]  -> later T[x][y]
  __shared__ __align__(16) float2 Ks[4096];   // K[e][y]  -> later xqkv[e][x]

  const size_t slab = (size_t)(b * Hq + h) * (Eq * Mq);
  {
    const float4* q4 = (const float4*)(Qft + slab);
    const float4* k4 = (const float4*)(Kft + slab);
    float4* qs4 = (float4*)Qs;
    float4* ks4 = (float4*)Ks;
    for (int i = tid; i < 2048; i += 256) { qs4[i] = q4[i]; ks4[i] = k4[i]; }
  }
  __syncthreads();

  // ---- A = Q^T K, thread tile 4x x 4y ----
  const int x0 = (tid >> 4) * 4;
  const int y0 = (tid & 15) * 4;
  float ar[4][4] = {}, ai[4][4] = {};
  for (int e = 0; e < 64; ++e) {
    float2 Qe[4], Ke[4];
#pragma unroll
    for (int i = 0; i < 4; ++i) Qe[i] = Qs[e * 64 + x0 + i];
#pragma unroll
    for (int j = 0; j < 4; ++j) Ke[j] = Ks[e * 64 + y0 + j];
#pragma unroll
    for (int i = 0; i < 4; ++i)
#pragma unroll
      for (int j = 0; j < 4; ++j) {
        ar[i][j] += Qe[i].x * Ke[j].x - Qe[i].y * Ke[j].y;
        ai[i][j] += Qe[i].x * Ke[j].y + Qe[i].y * Ke[j].x;
      }
  }

  // ---- complex tanh: tanh(x+iy) = (tx(1+ty^2) + i ty(1-tx^2)) / (1+tx^2 ty^2)
  float Tr[4][4], Ti[4][4];
#pragma unroll
  for (int i = 0; i < 4; ++i)
#pragma unroll
    for (int j = 0; j < 4; ++j) {
      float x = ar[i][j], y = ai[i][j];
      float tx = tanhf(x);
      float ty = tanf(y);
      float tx2 = tx * tx, ty2 = ty * ty;
      float inv = 1.0f / fmaf(tx2, ty2, 1.0f);
      Tr[i][j] = tx * (1.0f + ty2) * inv;
      Ti[i][j] = ty * (1.0f - tx2) * inv;
    }

  __syncthreads();                       // all reads of Qs done
#pragma unroll
  for (int i = 0; i < 4; ++i)
#pragma unroll
    for (int j = 0; j < 4; ++j)
      Qs[(x0 + i) * 64 + (y0 + j)] = make_float2(Tr[i][j], Ti[i][j]);  // T[x][y]
  __syncthreads();

  // ---- xqkv[e,x] = sum_y T[x,y] K[e,y], thread tile 4e x 4x ----
  const int e0 = (tid >> 4) * 4;
  const int xx0 = (tid & 15) * 4;
  float vr[4][4] = {}, vi[4][4] = {};
  for (int y = 0; y < 64; ++y) {
    float2 Tv[4], Kv[4];
#pragma unroll
    for (int j = 0; j < 4; ++j) Tv[j] = Qs[(xx0 + j) * 64 + y];
#pragma unroll
    for (int i = 0; i < 4; ++i) Kv[i] = Ks[(e0 + i) * 64 + y];
#pragma unroll
    for (int i = 0; i < 4; ++i)
#pragma unroll
      for (int j = 0; j < 4; ++j) {
        vr[i][j] += Tv[j].x * Kv[i].x - Tv[j].y * Kv[i].y;
        vi[i][j] += Tv[j].x * Kv[i].y + Tv[j].y * Kv[i].x;
      }
  }
  __syncthreads();                       // all reads of Ks done
#pragma unroll
  for (int i = 0; i < 4; ++i)
#pragma unroll
    for (int j = 0; j < 4; ++j)
      Ks[(e0 + i) * 64 + (xx0 + j)] = make_float2(vr[i][j], vi[i][j]);  // xqkv[e][x]
  __syncthreads();

  // ---- G[o,x] = scale_x * sum_e xqkv[e,x] * W[h,e,o,x], thread tile 4o x 4x
  const int o0 = (tid >> 4) * 4;
  const int x0w = (tid & 15) * 4;
  float gr[4][4] = {}, gi[4][4] = {};
  const float* __restrict__ wrb = w1r + (size_t)h * (Eq * Oq * Mq);
  const float* __restrict__ wib = w1i + (size_t)h * (Eq * Oq * Mq);
  for (int e = 0; e < 64; ++e) {
    float2 xv[4];
#pragma unroll
    for (int j = 0; j < 4; ++j) xv[j] = Ks[e * 64 + x0w + j];
#pragma unroll
    for (int i = 0; i < 4; ++i) {
      const float4 wr4 = *(const float4*)(wrb + ((size_t)(e * Oq + o0 + i)) * Mq + x0w);
      const float4 wi4 = *(const float4*)(wib + ((size_t)(e * Oq + o0 + i)) * Mq + x0w);
      const float wrA[4] = {wr4.x, wr4.y, wr4.z, wr4.w};
      const float wiA[4] = {wi4.x, wi4.y, wi4.z, wi4.w};
#pragma unroll
      for (int j = 0; j < 4; ++j) {
        gr[i][j] += xv[j].x * wrA[j] - xv[j].y * wiA[j];
        gi[i][j] += xv[j].x * wiA[j] + xv[j].y * wrA[j];
      }
    }
  }

  const float sc = 1.8626451492309570e-9f;  // 2^-29 = 1/(512*512*2048), exact
  float2* __restrict__ Gout = G + (size_t)(b * Hq + h) * (Oq * Mq);
#pragma unroll
  for (int i = 0; i < 4; ++i)
#pragma unroll
    for (int j = 0; j < 4; ++j) {
      const float s = ((x0w + j) == 0) ? sc : 2.0f * sc;  // irfft mode weight/L folded in
      Gout[(o0 + i) * Mq + x0w + j] = make_float2(gr[i][j] * s, gi[i][j] * s);
    }
}

// ---------------------------------------------------------------------------
// K3: out[b,h,o,t] = C[t] - S[t], out[b,h,o,2048-t] = C[t] + S[t], where
//   C[t] = sum_m Gr[o,m] cos(2pi m t/L), S[t] = sum_m Gi[o,m] sin(2pi m t/L).
// Mirror fold halves the FMAs. grid (8 pair-chunks of 128 t, H, B), block 256.
// Thread tile 8o x 4t. t=0 mirror skipped; t=1024 column (sum (-1)^m Gr)
// handled by chunk 0. Step twiddles: 128 exact per-block double-sincos.
// ---------------------------------------------------------------------------
__global__ __launch_bounds__(256) void irfft64_kernel(
    const float2* __restrict__ G, float* __restrict__ out) {
  const int tc = blockIdx.x;             // t in [tc*128, tc*128+128) -> [0,1024)
  const int h = blockIdx.y, b = blockIdx.z;
  const int tid = threadIdx.x;

  __shared__ float2 Gs[64 * 65];   // [m][o], +1 pad
  __shared__ float2 tws[128];      // step twiddles for this block's t-range

  if (tid < 128) {
    double ang = (double)(tc * 128 + tid) * 3.0679615757712823e-3;  // 2*pi/2048
    double sn, cs;
    sincos(ang, &sn, &cs);
    tws[tid] = make_float2((float)cs, (float)sn);
  }
  const size_t slab = (size_t)(b * Hq + h) * (Oq * Mq);
  for (int i = tid; i < 4096; i += 256) {
    const int o = i >> 6, m = i & 63;
    Gs[m * 65 + o] = G[slab + i];
  }
  __syncthreads();

  const int o0 = (tid >> 5) * 8;
  const int tl = (tid & 31) * 4;

  float ct[4], st[4], c[4], s[4];
#pragma unroll
  for (int tt = 0; tt < 4; ++tt) {
    float2 w = tws[tl + tt];
    ct[tt] = w.x; st[tt] = w.y;
    c[tt] = 1.0f; s[tt] = 0.0f;    // state at m = 0
  }

  float C[8][4] = {}, S[8][4] = {};
  for (int m = 0; m < 64; ++m) {
    float2 g[8];
#pragma unroll
    for (int i = 0; i < 8; ++i) g[i] = Gs[m * 65 + o0 + i];
#pragma unroll
    for (int tt = 0; tt < 4; ++tt) {
      const float cc = c[tt], ss = s[tt];
#pragma unroll
      for (int i = 0; i < 8; ++i) {
        C[i][tt] = fmaf(g[i].x, cc, C[i][tt]);
        S[i][tt] = fmaf(g[i].y, ss, S[i][tt]);
      }
      rot_step(c[tt], s[tt], ct[tt], st[tt]);
    }
  }

  const int t0 = tc * 128 + tl;
  float* __restrict__ obase = out + (size_t)(b * Hq + h) * (Oq * Lq);
#pragma unroll
  for (int i = 0; i < 8; ++i) {
    float* __restrict__ row = obase + (size_t)(o0 + i) * Lq;
    *(float4*)(row + t0) = make_float4(C[i][0] - S[i][0], C[i][1] - S[i][1],
                                       C[i][2] - S[i][2], C[i][3] - S[i][3]);
    // mirror writes t' = 2048-(t0+tt); odd offsets -> scalar stores (L2 merges)
#pragma unroll
    for (int tt = 0; tt < 4; ++tt) {
      if (t0 + tt > 0) row[2048 - t0 - tt] = C[i][tt] + S[i][tt];
    }
  }

  // t = 1024 column: out[o][1024] = sum_m (-1)^m Gr[o][m]
  if (tc == 0 && tid < 64) {
    float acc = 0.0f;
    for (int m = 0; m < 64; m += 2) {
      acc += Gs[m * 65 + tid].x;
      acc -= Gs[(m + 1) * 65 + tid].x;
    }
    obase[(size_t)tid * Lq + 1024] = acc;
  }
}

// ---------------------------------------------------------------------------
extern "C" void kernel_launch(void* const* d_in, const int* in_sizes, int n_in,
                              void* d_out, int out_size, void* d_ws, size_t ws_size,
                              hipStream_t stream) {
  const float* q = (const float*)d_in[0];
  const float* k = (const float*)d_in[1];
  // d_in[2] = v (unused by the reference forward)
  const float* w1r = (const float*)d_in[3];
  const float* w1i = (const float*)d_in[4];
  float* out = (float*)d_out;

  // Scratch: Qft/Kft live in d_out (33.6 MB of 256 MB; K3 overwrites all of
  // d_out afterwards). G (16.8 MB) lives in d_ws.
  float2* Qft = (float2*)d_out;
  float2* Kft = Qft + (size_t)Bq * Hq * Eq * Mq;   // +2,097,152 float2
  float2* G = (float2*)d_ws;

  dft64_kernel<<<dim3(Hq, Bq, 2), 256, 0, stream>>>(q, k, Qft, Kft);
  attn_kernel<<<dim3(Hq, Bq), 256, 0, stream>>>(Qft, Kft, w1r, w1i, G);
  irfft64_kernel<<<dim3(8, Hq, Bq), 256, 0, stream>>>(G, out);
}